// Round 3
// baseline (79.580 us; speedup 1.0000x reference)
//
#include <hip/hip_runtime.h>
#include <hip/hip_bf16.h>

// GraspHD encoder:
//   counts[t,p,n] = sum of 8x8 block of x            (T=100, P=2, NB=300)
//   bundled[d]    = sum_{t,p,n} sin(counts*w[d]) * pos[n,d]*pol[p,d]*time[t,d]
//   out[d]        = sign(bundled[d])                 (D=4096)
// pos/pol/time are exactly +-1.0f. Fold the sign product INTO the sin
// argument's sign bit (sin(s*x) = s*sin(x) for s=+-1).
// sin via hardware v_fract + v_sin (input in revolutions), w pre-scaled 1/2pi.
// Work = 15000 "quads" (t-pair x n), distributed as balanced contiguous
// ranges over a grid that exactly fills the machine (2048 blocks = 8/CU).
// counts are stored in quad layout so k_encode reads them as wave-uniform
// s_load_dwordx4 -> no LDS, no barriers in the hot loop.

#define T_ 100
#define P_ 2
#define H_ 120
#define W_ 160
#define BS_ 8
#define WB_ 20
#define NB_ 300
#define D_ 4096
#define NTC_ 50          // t-pairs
#define NQ_ (NTC_ * NB_) // 15000 quads

// ---------------- kernel 1: per-block event counts (quad layout) ----------------
__global__ __launch_bounds__(256) void k_counts(const float* __restrict__ x,
                                                float* __restrict__ cq) {
    int idx = blockIdx.x * 256 + threadIdx.x;           // (t*P + p)*NB + n
    if (idx >= T_ * P_ * NB_) return;
    int n  = idx % NB_;
    int tp = idx / NB_;
    int p  = tp & 1;
    int t  = tp >> 1;
    int hb = n / WB_;
    int wb = n % WB_;
    const float* base = x + ((size_t)tp * H_ + hb * BS_) * W_ + wb * BS_;
    float s = 0.f;
#pragma unroll
    for (int i = 0; i < BS_; ++i) {
        const float4* row = reinterpret_cast<const float4*>(base + i * W_);
        float4 a = row[0];
        float4 b = row[1];
        s += a.x + a.y + a.z + a.w + b.x + b.y + b.z + b.w;
    }
    int tc = t >> 1, tl = t & 1;
    cq[((size_t)(tc * NB_ + n) << 2) + tl * 2 + p] = s;
}

// ---------------- kernel 2: main bind+bundle partial sums ----------------
// grid (D/256, gy). Block y owns quads [y*NQ/gy, (y+1)*NQ/gy).
__global__ __launch_bounds__(256) void k_encode(const float4* __restrict__ cq,
                                                const float* __restrict__ proj_w,
                                                const float* __restrict__ pos_hv,
                                                const float* __restrict__ pol_hv,
                                                const float* __restrict__ time_hv,
                                                float* __restrict__ partial,
                                                int gy) {
    const int d = blockIdx.x * 256 + threadIdx.x;
    const int y = blockIdx.y;
    int       q  = (int)(((long long)y * NQ_) / gy);
    const int q1 = (int)(((long long)(y + 1) * NQ_) / gy);

    const float wp = proj_w[d] * 0.15915494309189535f;   // 1/(2*pi)
    const unsigned SGN = 0x80000000u;
    const unsigned uw  = __float_as_uint(wp);
    const unsigned pl0 = __float_as_uint(pol_hv[d]) & SGN;
    const unsigned pl1 = __float_as_uint(pol_hv[D_ + d]) & SGN;

    float a0 = 0.f, a1 = 0.f, a2 = 0.f, a3 = 0.f;

    while (q < q1) {
        int tc = q / NB_;
        int n  = q - tc * NB_;
        int qe = min(q1, (tc + 1) * NB_);
        int t0 = tc * 2;
        unsigned tpa = __float_as_uint(time_hv[(size_t)t0 * D_ + d]) & SGN;
        unsigned tpb = __float_as_uint(time_hv[(size_t)(t0 + 1) * D_ + d]) & SGN;
        const unsigned u00 = uw ^ (tpa ^ pl0);
        const unsigned u01 = uw ^ (tpa ^ pl1);
        const unsigned u10 = uw ^ (tpb ^ pl0);
        const unsigned u11 = uw ^ (tpb ^ pl1);
        const float* pp = pos_hv + (size_t)n * D_ + d;
#pragma unroll 2
        for (; q < qe; ++q) {
            float4 c = cq[q];                            // wave-uniform -> s_load
            unsigned mn = __float_as_uint(*pp) & SGN;
            pp += D_;
            a0 += __builtin_amdgcn_sinf(__builtin_amdgcn_fractf(c.x * __uint_as_float(u00 ^ mn)));
            a1 += __builtin_amdgcn_sinf(__builtin_amdgcn_fractf(c.y * __uint_as_float(u01 ^ mn)));
            a2 += __builtin_amdgcn_sinf(__builtin_amdgcn_fractf(c.z * __uint_as_float(u10 ^ mn)));
            a3 += __builtin_amdgcn_sinf(__builtin_amdgcn_fractf(c.w * __uint_as_float(u11 ^ mn)));
        }
    }

    partial[(size_t)y * D_ + d] = (a0 + a1) + (a2 + a3);
}

// ---------------- kernel 3: deterministic reduce + sign ----------------
__global__ __launch_bounds__(256) void k_reduce(const float* __restrict__ partial,
                                                float* __restrict__ out, int gy) {
    int d = blockIdx.x * 256 + threadIdx.x;
    float a = 0.f;
    for (int g = 0; g < gy; ++g) a += partial[(size_t)g * D_ + d];
    out[d] = (a > 0.f) ? 1.f : ((a < 0.f) ? -1.f : 0.f);
}

extern "C" void kernel_launch(void* const* d_in, const int* in_sizes, int n_in,
                              void* d_out, int out_size, void* d_ws, size_t ws_size,
                              hipStream_t stream) {
    const float* x       = (const float*)d_in[0];
    const float* proj_w  = (const float*)d_in[1];
    const float* pos_hv  = (const float*)d_in[2];
    const float* pol_hv  = (const float*)d_in[3];
    const float* time_hv = (const float*)d_in[4];
    float* out = (float*)d_out;

    // ws layout: counts_q (15000 float4 = 240 KB) at 0, partials at 256 KiB.
    float* counts_q = (float*)d_ws;
    float* partial  = (float*)((char*)d_ws + (256u << 10));

    // gy*D*4 bytes of partials must fit after the 256 KiB counts region.
    int gy = (ws_size >= (256u << 10) + 128u * D_ * 4u + 1024u) ? 128 : 64;

    {
        int total = T_ * P_ * NB_;
        k_counts<<<dim3((total + 255) / 256), dim3(256), 0, stream>>>(x, counts_q);
    }
    {
        dim3 grid(D_ / 256, gy);
        k_encode<<<grid, dim3(256), 0, stream>>>((const float4*)counts_q, proj_w,
                                                 pos_hv, pol_hv, time_hv, partial, gy);
    }
    k_reduce<<<dim3(D_ / 256), dim3(256), 0, stream>>>(partial, out, gy);
}

// Round 4
// 75.362 us; speedup vs baseline: 1.0560x; 1.0560x over previous
//
#include <hip/hip_runtime.h>
#include <hip/hip_bf16.h>

// GraspHD encoder:
//   counts[t,p,n] = sum of 8x8 block of x            (T=100, P=2, NB=300)
//   bundled[d]    = sum_{t,p,n} sin(counts*w[d]) * pos[n,d]*pol[p,d]*time[t,d]
//   out[d]        = sign(bundled[d])                 (D=4096)
// pos/pol/time are exactly +-1.0f: fold sign product into the sin argument's
// sign bit (sin(s*x) = s*sin(x)).  sin = v_fract + v_sin (revolutions).
//
// R3 restructure: block = (d-slice 256) x (n-range 12) x (tc-range 10).
// Loop n outer / tc inner: pos sign loaded ONCE per n (reg-resident across
// the unrolled tc loop), 20 time-sign words hoisted to regs per block,
// counts transposed to [n][tc] quads -> contiguous wave-uniform s_loads.
// Cache traffic drops ~245 MB -> ~70 MB per dispatch.

#define T_ 100
#define P_ 2
#define H_ 120
#define W_ 160
#define BS_ 8
#define WB_ 20
#define NB_ 300
#define D_ 4096
#define NTC_ 50            // t-pairs
#define NR_ 25             // n-ranges, 12 n each
#define TR_ 5              // tc-ranges, 10 tc each
#define GY_ (NR_ * TR_)    // 125 y-blocks

// ---------------- kernel 1: per-block event counts ([n][tc] quad layout) ----
__global__ __launch_bounds__(256) void k_counts(const float* __restrict__ x,
                                                float* __restrict__ cq) {
    int idx = blockIdx.x * 256 + threadIdx.x;           // (t*P + p)*NB + n
    if (idx >= T_ * P_ * NB_) return;
    int n  = idx % NB_;
    int tp = idx / NB_;
    int p  = tp & 1;
    int t  = tp >> 1;
    int hb = n / WB_;
    int wb = n % WB_;
    const float* base = x + ((size_t)tp * H_ + hb * BS_) * W_ + wb * BS_;
    float s = 0.f;
#pragma unroll
    for (int i = 0; i < BS_; ++i) {
        const float4* row = reinterpret_cast<const float4*>(base + i * W_);
        float4 a = row[0];
        float4 b = row[1];
        s += a.x + a.y + a.z + a.w + b.x + b.y + b.z + b.w;
    }
    int tc = t >> 1, tl = t & 1;
    // quad[n][tc] = {c(2tc,p0), c(2tc,p1), c(2tc+1,p0), c(2tc+1,p1)}
    cq[((size_t)(n * NTC_ + tc) << 2) + tl * 2 + p] = s;
}

// ---------------- kernel 2: main bind+bundle partial sums ----------------
// grid (D/256, GY_).  y -> (tcr, nr): tc in [tcr*10,+10), n in [nr*12,+12).
__global__ __launch_bounds__(256) void k_encode(const float4* __restrict__ cq,
                                                const float* __restrict__ proj_w,
                                                const float* __restrict__ pos_hv,
                                                const float* __restrict__ pol_hv,
                                                const float* __restrict__ time_hv,
                                                float* __restrict__ partial) {
    const int d   = blockIdx.x * 256 + threadIdx.x;
    const int tcr = blockIdx.y / NR_;
    const int nr  = blockIdx.y - tcr * NR_;
    const int n0  = nr * 12;
    const int tc0 = tcr * 10;
    const int t0  = tcr * 20;

    const unsigned SGN = 0x80000000u;
    const float wp = proj_w[d] * 0.15915494309189535f;   // 1/(2*pi)
    const unsigned uw  = __float_as_uint(wp);
    const unsigned pl0 = __float_as_uint(pol_hv[d]) & SGN;
    const unsigned pl1 = __float_as_uint(pol_hv[D_ + d]) & SGN;

    // hoist 20 time-sign words into registers (static-indexed, unrolled)
    unsigned ta[20];
#pragma unroll
    for (int k = 0; k < 20; ++k)
        ta[k] = __float_as_uint(time_hv[(size_t)(t0 + k) * D_ + d]) & SGN;

    float a0 = 0.f, a1 = 0.f, a2 = 0.f, a3 = 0.f;

    for (int j = 0; j < 12; ++j) {
        const int n = n0 + j;
        const unsigned mn = __float_as_uint(pos_hv[(size_t)n * D_ + d]) & SGN;
        const unsigned b0 = (uw ^ pl0) ^ mn;
        const unsigned b1 = (uw ^ pl1) ^ mn;
        const float4* cp = cq + (size_t)n * NTC_ + tc0;   // wave-uniform
#pragma unroll
        for (int k = 0; k < 10; ++k) {
            float4 c = cp[k];
            const unsigned ua = ta[2 * k];
            const unsigned ub = ta[2 * k + 1];
            a0 += __builtin_amdgcn_sinf(__builtin_amdgcn_fractf(c.x * __uint_as_float(b0 ^ ua)));
            a1 += __builtin_amdgcn_sinf(__builtin_amdgcn_fractf(c.y * __uint_as_float(b1 ^ ua)));
            a2 += __builtin_amdgcn_sinf(__builtin_amdgcn_fractf(c.z * __uint_as_float(b0 ^ ub)));
            a3 += __builtin_amdgcn_sinf(__builtin_amdgcn_fractf(c.w * __uint_as_float(b1 ^ ub)));
        }
    }

    partial[(size_t)blockIdx.y * D_ + d] = (a0 + a1) + (a2 + a3);
}

// ---------------- kernel 3: deterministic reduce + sign ----------------
__global__ __launch_bounds__(256) void k_reduce(const float* __restrict__ partial,
                                                float* __restrict__ out) {
    int d = blockIdx.x * 256 + threadIdx.x;
    float a = 0.f;
#pragma unroll
    for (int g = 0; g < GY_; ++g) a += partial[(size_t)g * D_ + d];
    out[d] = (a > 0.f) ? 1.f : ((a < 0.f) ? -1.f : 0.f);
}

extern "C" void kernel_launch(void* const* d_in, const int* in_sizes, int n_in,
                              void* d_out, int out_size, void* d_ws, size_t ws_size,
                              hipStream_t stream) {
    const float* x       = (const float*)d_in[0];
    const float* proj_w  = (const float*)d_in[1];
    const float* pos_hv  = (const float*)d_in[2];
    const float* pol_hv  = (const float*)d_in[3];
    const float* time_hv = (const float*)d_in[4];
    float* out = (float*)d_out;

    // ws layout: counts_q (15000 float4 = 240 KB) at 0, partials (125*D f32)
    // at 256 KiB (total 2.25 MB; R2 already used 2.3 MB successfully).
    float* counts_q = (float*)d_ws;
    float* partial  = (float*)((char*)d_ws + (256u << 10));

    {
        int total = T_ * P_ * NB_;
        k_counts<<<dim3((total + 255) / 256), dim3(256), 0, stream>>>(x, counts_q);
    }
    {
        dim3 grid(D_ / 256, GY_);
        k_encode<<<grid, dim3(256), 0, stream>>>((const float4*)counts_q, proj_w,
                                                 pos_hv, pol_hv, time_hv, partial);
    }
    k_reduce<<<dim3(D_ / 256), dim3(256), 0, stream>>>(partial, out);
}

// Round 5
// 50.633 us; speedup vs baseline: 1.5717x; 1.4884x over previous
//
#include <hip/hip_runtime.h>
#include <hip/hip_bf16.h>

// GraspHD encoder:
//   counts[t,p,n] = sum of 8x8 block of x            (T=100, P=2, NB=300)
//   bundled[d]    = sum_{t,p,n} sin(counts*w[d]) * pos[n,d]*pol[p,d]*time[t,d]
//   out[d]        = sign(bundled[d])                 (D=4096)
// pos/pol/time are exactly +-1.0f: fold the sign product into the sin
// argument's sign bit (sin(s*x) = s*sin(x)).
// sin = HW v_sin (input in REVOLUTIONS, valid range +-256; our max |arg|
// ~41 rev) -> no v_fract needed.  w pre-scaled by 1/2pi.
//
// R4: counts stay in R1's linear [t][p][n] layout (coalesced write);
// k_encode reads each quad as 4 wave-uniform s_loads (imm offsets).
// Reduce is a 2-stage parallel tree (400 + 16 blocks) instead of a
// 16-block serial loop.

#define T_ 100
#define P_ 2
#define H_ 120
#define W_ 160
#define BS_ 8
#define WB_ 20
#define NB_ 300
#define D_ 4096
#define NTC_ 50            // t-pairs
#define NR_ 25             // n-ranges, 12 n each
#define TR_ 5              // tc-ranges, 10 tc each
#define GY_ (NR_ * TR_)    // 125 encode y-blocks

// ---------------- kernel 1: per-block event counts (linear layout) --------
__global__ __launch_bounds__(256) void k_counts(const float* __restrict__ x,
                                                float* __restrict__ counts) {
    int idx = blockIdx.x * 256 + threadIdx.x;           // (t*P + p)*NB + n
    if (idx >= T_ * P_ * NB_) return;
    int n  = idx % NB_;
    int tp = idx / NB_;
    int hb = n / WB_;
    int wb = n % WB_;
    const float* base = x + ((size_t)tp * H_ + hb * BS_) * W_ + wb * BS_;
    float s = 0.f;
#pragma unroll
    for (int i = 0; i < BS_; ++i) {
        const float4* row = reinterpret_cast<const float4*>(base + i * W_);
        float4 a = row[0];
        float4 b = row[1];
        s += a.x + a.y + a.z + a.w + b.x + b.y + b.z + b.w;
    }
    counts[idx] = s;                                    // coalesced
}

// ---------------- kernel 2: main bind+bundle partial sums ----------------
// grid (D/256, GY_).  y -> (tcr, nr): tc in [tcr*10,+10), n in [nr*12,+12).
// counts[(t*2+p)*300 + n]; quad (tc,n) = offsets tc*1200 + {0,300,600,900} + n.
__global__ __launch_bounds__(256) void k_encode(const float* __restrict__ counts,
                                                const float* __restrict__ proj_w,
                                                const float* __restrict__ pos_hv,
                                                const float* __restrict__ pol_hv,
                                                const float* __restrict__ time_hv,
                                                float* __restrict__ partial) {
    const int d   = blockIdx.x * 256 + threadIdx.x;
    const int tcr = blockIdx.y / NR_;
    const int nr  = blockIdx.y - tcr * NR_;
    const int n0  = nr * 12;
    const int tc0 = tcr * 10;
    const int t0  = tcr * 20;

    const unsigned SGN = 0x80000000u;
    const float wp = proj_w[d] * 0.15915494309189535f;   // 1/(2*pi)
    const unsigned uw  = __float_as_uint(wp);
    const unsigned pl0 = __float_as_uint(pol_hv[d]) & SGN;
    const unsigned pl1 = __float_as_uint(pol_hv[D_ + d]) & SGN;

    // hoist 20 time-sign words into registers (static-indexed, unrolled)
    unsigned ta[20];
#pragma unroll
    for (int k = 0; k < 20; ++k)
        ta[k] = __float_as_uint(time_hv[(size_t)(t0 + k) * D_ + d]) & SGN;

    float a0 = 0.f, a1 = 0.f, a2 = 0.f, a3 = 0.f;

    // wave-uniform base for this block's count quads
    const float* cb0 = counts + tc0 * 1200 + n0;

    for (int j = 0; j < 12; ++j) {
        const int n = n0 + j;
        const unsigned mn = __float_as_uint(pos_hv[(size_t)n * D_ + d]) & SGN;
        const unsigned b0 = (uw ^ pl0) ^ mn;
        const unsigned b1 = (uw ^ pl1) ^ mn;
        const float* cb = cb0 + j;                       // wave-uniform
#pragma unroll
        for (int k = 0; k < 10; ++k) {
            // 4 wave-uniform scalar loads, compile-time imm offsets
            float c0 = cb[k * 1200 + 0];                 // t=2tc,   p=0
            float c1 = cb[k * 1200 + 300];               // t=2tc,   p=1
            float c2 = cb[k * 1200 + 600];               // t=2tc+1, p=0
            float c3 = cb[k * 1200 + 900];               // t=2tc+1, p=1
            const unsigned ua = ta[2 * k];
            const unsigned ub = ta[2 * k + 1];
            a0 += __builtin_amdgcn_sinf(c0 * __uint_as_float(b0 ^ ua));
            a1 += __builtin_amdgcn_sinf(c1 * __uint_as_float(b1 ^ ua));
            a2 += __builtin_amdgcn_sinf(c2 * __uint_as_float(b0 ^ ub));
            a3 += __builtin_amdgcn_sinf(c3 * __uint_as_float(b1 ^ ub));
        }
    }

    partial[(size_t)blockIdx.y * D_ + d] = (a0 + a1) + (a2 + a3);
}

// ---------------- kernel 3a: reduce stage A (125 -> 25 rows) -------------
__global__ __launch_bounds__(256) void k_reduceA(const float* __restrict__ partial,
                                                 float* __restrict__ p2) {
    int d = blockIdx.x * 256 + threadIdx.x;
    int g0 = blockIdx.y * TR_;
    float a = 0.f;
#pragma unroll
    for (int g = 0; g < TR_; ++g) a += partial[(size_t)(g0 + g) * D_ + d];
    p2[(size_t)blockIdx.y * D_ + d] = a;
}

// ---------------- kernel 3b: reduce stage B (25 rows) + sign -------------
__global__ __launch_bounds__(256) void k_reduceB(const float* __restrict__ p2,
                                                 float* __restrict__ out) {
    int d = blockIdx.x * 256 + threadIdx.x;
    float a = 0.f;
#pragma unroll
    for (int g = 0; g < NR_; ++g) a += p2[(size_t)g * D_ + d];
    out[d] = (a > 0.f) ? 1.f : ((a < 0.f) ? -1.f : 0.f);
}

extern "C" void kernel_launch(void* const* d_in, const int* in_sizes, int n_in,
                              void* d_out, int out_size, void* d_ws, size_t ws_size,
                              hipStream_t stream) {
    const float* x       = (const float*)d_in[0];
    const float* proj_w  = (const float*)d_in[1];
    const float* pos_hv  = (const float*)d_in[2];
    const float* pol_hv  = (const float*)d_in[3];
    const float* time_hv = (const float*)d_in[4];
    float* out = (float*)d_out;

    // ws layout: counts (60000 f32, 240 KB) at 0; partial (125*D f32, 2 MB)
    // at 256 KiB; p2 (25*D f32, 400 KB) after that.  Total ~2.66 MB.
    float* counts  = (float*)d_ws;
    float* partial = (float*)((char*)d_ws + (256u << 10));
    float* p2      = (float*)((char*)d_ws + (256u << 10) + (size_t)GY_ * D_ * 4);

    {
        int total = T_ * P_ * NB_;
        k_counts<<<dim3((total + 255) / 256), dim3(256), 0, stream>>>(x, counts);
    }
    {
        dim3 grid(D_ / 256, GY_);
        k_encode<<<grid, dim3(256), 0, stream>>>(counts, proj_w, pos_hv, pol_hv,
                                                 time_hv, partial);
    }
    k_reduceA<<<dim3(D_ / 256, NR_), dim3(256), 0, stream>>>(partial, p2);
    k_reduceB<<<dim3(D_ / 256), dim3(256), 0, stream>>>(p2, out);
}

// Round 6
// 48.252 us; speedup vs baseline: 1.6493x; 1.0493x over previous
//
#include <hip/hip_runtime.h>
#include <hip/hip_bf16.h>

// GraspHD encoder:
//   counts[t,p,n] = sum of 8x8 block of x            (T=100, P=2, NB=300)
//   bundled[d]    = sum_{t,p,n} sin(counts*w[d]) * pos[n,d]*pol[p,d]*time[t,d]
//   out[d]        = sign(bundled[d])                 (D=4096)
// pos/pol/time are exactly +-1.0f: fold the sign product into the sin
// argument's sign bit (sin(s*x) = s*sin(x)).
// sin = HW v_sin (input in REVOLUTIONS, range +-256; max |arg| ~41 rev),
// w pre-scaled by 1/2pi.
//
// R5: counts stored in quad layout [tc][n][{t0p0,t0p1,t1p0,t1p1}] so the
// encode inner loop (n, 12 iters, fully unrolled) reads 192 contiguous
// wave-uniform bytes -> compiler merges into s_load_dwordx16 batches.
// pos sign words hoisted into registers once per block (X0/X1[12]),
// reused across all 10 tc iterations. Time signs loaded 2/k-iter.

#define T_ 100
#define P_ 2
#define H_ 120
#define W_ 160
#define BS_ 8
#define WB_ 20
#define NB_ 300
#define D_ 4096
#define NTC_ 50            // t-pairs
#define NR_ 25             // n-ranges, 12 n each
#define TR_ 5              // tc-ranges, 10 tc each
#define GY_ (NR_ * TR_)    // 125 encode y-blocks

// ---------------- kernel 1: per-block event counts (quad layout) ----------
// cq[((tc*300)+n)*4 + tl*2 + p]; reads stay fully coalesced per (t,p) row.
__global__ __launch_bounds__(256) void k_counts(const float* __restrict__ x,
                                                float* __restrict__ cq) {
    int idx = blockIdx.x * 256 + threadIdx.x;           // (t*P + p)*NB + n
    if (idx >= T_ * P_ * NB_) return;
    int n  = idx % NB_;
    int tp = idx / NB_;
    int p  = tp & 1;
    int t  = tp >> 1;
    int hb = n / WB_;
    int wb = n % WB_;
    const float* base = x + ((size_t)tp * H_ + hb * BS_) * W_ + wb * BS_;
    float s = 0.f;
#pragma unroll
    for (int i = 0; i < BS_; ++i) {
        const float4* row = reinterpret_cast<const float4*>(base + i * W_);
        float4 a = row[0];
        float4 b = row[1];
        s += a.x + a.y + a.z + a.w + b.x + b.y + b.z + b.w;
    }
    cq[(((size_t)(t >> 1) * NB_ + n) << 2) + (t & 1) * 2 + p] = s;
}

// ---------------- kernel 2: main bind+bundle partial sums ----------------
// grid (D/256, GY_).  y -> (tcr, nr): tc in [tcr*10,+10), n in [nr*12,+12).
__global__ __launch_bounds__(256) void k_encode(const float4* __restrict__ cq,
                                                const float* __restrict__ proj_w,
                                                const float* __restrict__ pos_hv,
                                                const float* __restrict__ pol_hv,
                                                const float* __restrict__ time_hv,
                                                float* __restrict__ partial) {
    const int d   = blockIdx.x * 256 + threadIdx.x;
    const int tcr = blockIdx.y / NR_;
    const int nr  = blockIdx.y - tcr * NR_;
    const int n0  = nr * 12;
    const int tc0 = tcr * 10;

    const unsigned SGN = 0x80000000u;
    const float wp = proj_w[d] * 0.15915494309189535f;   // 1/(2*pi)
    const unsigned uw  = __float_as_uint(wp);
    const unsigned pl0 = __float_as_uint(pol_hv[d]) & SGN;
    const unsigned pl1 = __float_as_uint(pol_hv[D_ + d]) & SGN;

    // hoist 12 pos sign words, pre-xored with w and polarity (registers)
    unsigned X0[12], X1[12];
#pragma unroll
    for (int j = 0; j < 12; ++j) {
        unsigned mn = __float_as_uint(pos_hv[(size_t)(n0 + j) * D_ + d]) & SGN;
        X0[j] = (uw ^ pl0) ^ mn;
        X1[j] = (uw ^ pl1) ^ mn;
    }

    float a0 = 0.f, a1 = 0.f, a2 = 0.f, a3 = 0.f;

    const float4* cb = cq + (size_t)tc0 * NB_ + n0;       // wave-uniform
    const float*  th = time_hv + (size_t)(tc0 * 2) * D_ + d;

#pragma unroll 2
    for (int k = 0; k < 10; ++k) {
        const unsigned ua = __float_as_uint(th[0]) & SGN;           // t = 2(tc0+k)
        const unsigned ub = __float_as_uint(th[(size_t)D_]) & SGN;  // t = 2(tc0+k)+1
        th += 2 * (size_t)D_;
        const float4* ck = cb + (size_t)k * NB_;
#pragma unroll
        for (int j = 0; j < 12; ++j) {
            float4 c = ck[j];                             // contiguous s_loads
            a0 += __builtin_amdgcn_sinf(c.x * __uint_as_float(X0[j] ^ ua));
            a1 += __builtin_amdgcn_sinf(c.y * __uint_as_float(X1[j] ^ ua));
            a2 += __builtin_amdgcn_sinf(c.z * __uint_as_float(X0[j] ^ ub));
            a3 += __builtin_amdgcn_sinf(c.w * __uint_as_float(X1[j] ^ ub));
        }
    }

    partial[(size_t)blockIdx.y * D_ + d] = (a0 + a1) + (a2 + a3);
}

// ---------------- kernel 3a: reduce stage A (125 -> 25 rows) -------------
__global__ __launch_bounds__(256) void k_reduceA(const float* __restrict__ partial,
                                                 float* __restrict__ p2) {
    int d = blockIdx.x * 256 + threadIdx.x;
    int g0 = blockIdx.y * TR_;
    float a = 0.f;
#pragma unroll
    for (int g = 0; g < TR_; ++g) a += partial[(size_t)(g0 + g) * D_ + d];
    p2[(size_t)blockIdx.y * D_ + d] = a;
}

// ---------------- kernel 3b: reduce stage B (25 rows) + sign -------------
__global__ __launch_bounds__(256) void k_reduceB(const float* __restrict__ p2,
                                                 float* __restrict__ out) {
    int d = blockIdx.x * 256 + threadIdx.x;
    float a = 0.f;
#pragma unroll
    for (int g = 0; g < NR_; ++g) a += p2[(size_t)g * D_ + d];
    out[d] = (a > 0.f) ? 1.f : ((a < 0.f) ? -1.f : 0.f);
}

extern "C" void kernel_launch(void* const* d_in, const int* in_sizes, int n_in,
                              void* d_out, int out_size, void* d_ws, size_t ws_size,
                              hipStream_t stream) {
    const float* x       = (const float*)d_in[0];
    const float* proj_w  = (const float*)d_in[1];
    const float* pos_hv  = (const float*)d_in[2];
    const float* pol_hv  = (const float*)d_in[3];
    const float* time_hv = (const float*)d_in[4];
    float* out = (float*)d_out;

    // ws layout: counts_q (15000 float4, 240 KB) at 0; partial (125*D f32,
    // 2 MB) at 256 KiB; p2 (25*D f32, 400 KB) after that.  Total ~2.66 MB.
    float* counts_q = (float*)d_ws;
    float* partial  = (float*)((char*)d_ws + (256u << 10));
    float* p2       = (float*)((char*)d_ws + (256u << 10) + (size_t)GY_ * D_ * 4);

    {
        int total = T_ * P_ * NB_;
        k_counts<<<dim3((total + 255) / 256), dim3(256), 0, stream>>>(x, counts_q);
    }
    {
        dim3 grid(D_ / 256, GY_);
        k_encode<<<grid, dim3(256), 0, stream>>>((const float4*)counts_q, proj_w,
                                                 pos_hv, pol_hv, time_hv, partial);
    }
    k_reduceA<<<dim3(D_ / 256, NR_), dim3(256), 0, stream>>>(partial, p2);
    k_reduceB<<<dim3(D_ / 256), dim3(256), 0, stream>>>(p2, out);
}

// Round 7
// 47.844 us; speedup vs baseline: 1.6633x; 1.0085x over previous
//
#include <hip/hip_runtime.h>
#include <hip/hip_bf16.h>

// GraspHD encoder:
//   counts[t,p,n] = sum of 8x8 block of x            (T=100, P=2, NB=300)
//   bundled[d]    = sum_{t,p,n} sin(counts*w[d]) * pos[n,d]*pol[p,d]*time[t,d]
//   out[d]        = sign(bundled[d])                 (D=4096)
// pos/pol/time are exactly +-1.0f: fold the sign product into the sin
// argument's sign bit (sin(s*x) = s*sin(x)).
// sin = HW v_sin (input in REVOLUTIONS, range +-256; max |arg| ~41 rev),
// w pre-scaled by 1/2pi.
//
// R6: all per-block sign words (12 pos x 2 pol pre-xored, 20 time) hoisted
// into registers in the prologue -> the hot loop has ZERO vector-memory ops;
// only wave-uniform s_loads of the contiguous count quads remain, and the
// fully-unrolled k-loop lets the scheduler issue them iterations ahead.
// Reduce is a single 64-block kernel (5 waves x 25 rows each + LDS combine).

#define T_ 100
#define P_ 2
#define H_ 120
#define W_ 160
#define BS_ 8
#define WB_ 20
#define NB_ 300
#define D_ 4096
#define NTC_ 50            // t-pairs
#define NR_ 25             // n-ranges, 12 n each
#define TR_ 5              // tc-ranges, 10 tc each
#define GY_ (NR_ * TR_)    // 125 encode y-blocks

// ---------------- kernel 1: per-block event counts (quad layout) ----------
// cq[((tc*300)+n)*4 + tl*2 + p]
__global__ __launch_bounds__(256) void k_counts(const float* __restrict__ x,
                                                float* __restrict__ cq) {
    int idx = blockIdx.x * 256 + threadIdx.x;           // (t*P + p)*NB + n
    if (idx >= T_ * P_ * NB_) return;
    int n  = idx % NB_;
    int tp = idx / NB_;
    int p  = tp & 1;
    int t  = tp >> 1;
    int hb = n / WB_;
    int wb = n % WB_;
    const float* base = x + ((size_t)tp * H_ + hb * BS_) * W_ + wb * BS_;
    float s = 0.f;
#pragma unroll
    for (int i = 0; i < BS_; ++i) {
        const float4* row = reinterpret_cast<const float4*>(base + i * W_);
        float4 a = row[0];
        float4 b = row[1];
        s += a.x + a.y + a.z + a.w + b.x + b.y + b.z + b.w;
    }
    cq[(((size_t)(t >> 1) * NB_ + n) << 2) + (t & 1) * 2 + p] = s;
}

// ---------------- kernel 2: main bind+bundle partial sums ----------------
// grid (D/256, GY_).  y -> (tcr, nr): tc in [tcr*10,+10), n in [nr*12,+12).
__global__ __launch_bounds__(256, 8) void k_encode(const float4* __restrict__ cq,
                                                   const float* __restrict__ proj_w,
                                                   const float* __restrict__ pos_hv,
                                                   const float* __restrict__ pol_hv,
                                                   const float* __restrict__ time_hv,
                                                   float* __restrict__ partial) {
    const int d   = blockIdx.x * 256 + threadIdx.x;
    const int tcr = blockIdx.y / NR_;
    const int nr  = blockIdx.y - tcr * NR_;
    const int n0  = nr * 12;
    const int tc0 = tcr * 10;
    const int t0  = tcr * 20;

    const unsigned SGN = 0x80000000u;
    const float wp = proj_w[d] * 0.15915494309189535f;   // 1/(2*pi)
    const unsigned uw  = __float_as_uint(wp);
    const unsigned pl0 = __float_as_uint(pol_hv[d]) & SGN;
    const unsigned pl1 = __float_as_uint(pol_hv[D_ + d]) & SGN;

    // hoist 20 time sign words (static-indexed -> registers)
    unsigned ta[20];
#pragma unroll
    for (int k = 0; k < 20; ++k)
        ta[k] = __float_as_uint(time_hv[(size_t)(t0 + k) * D_ + d]) & SGN;

    // hoist 12 pos sign words, pre-xored with w and polarity
    unsigned X0[12], X1[12];
#pragma unroll
    for (int j = 0; j < 12; ++j) {
        unsigned mn = __float_as_uint(pos_hv[(size_t)(n0 + j) * D_ + d]) & SGN;
        X0[j] = (uw ^ pl0) ^ mn;
        X1[j] = (uw ^ pl1) ^ mn;
    }

    float a0 = 0.f, a1 = 0.f, a2 = 0.f, a3 = 0.f;

    const float4* cb = cq + (size_t)tc0 * NB_ + n0;       // wave-uniform

#pragma unroll
    for (int k = 0; k < 10; ++k) {
        const unsigned ua = ta[2 * k];
        const unsigned ub = ta[2 * k + 1];
        const float4* ck = cb + (size_t)k * NB_;
#pragma unroll
        for (int j = 0; j < 12; ++j) {
            float4 c = ck[j];                             // contiguous s_loads
            a0 += __builtin_amdgcn_sinf(c.x * __uint_as_float(X0[j] ^ ua));
            a1 += __builtin_amdgcn_sinf(c.y * __uint_as_float(X1[j] ^ ua));
            a2 += __builtin_amdgcn_sinf(c.z * __uint_as_float(X0[j] ^ ub));
            a3 += __builtin_amdgcn_sinf(c.w * __uint_as_float(X1[j] ^ ub));
        }
    }

    partial[(size_t)blockIdx.y * D_ + d] = (a0 + a1) + (a2 + a3);
}

// ---------------- kernel 3: single-launch reduce + sign ------------------
// grid 64 blocks, block (64,5) = 5 waves. Wave w sums rows [w*25, w*25+25)
// for its 64 d's; LDS combine; wave 0 writes sign. Deterministic order.
__global__ __launch_bounds__(320) void k_reduce(const float* __restrict__ partial,
                                                float* __restrict__ out) {
    __shared__ float red[TR_][64];
    const int lane = threadIdx.x;          // 0..63
    const int w    = threadIdx.y;          // 0..4
    const int d    = blockIdx.x * 64 + lane;
    float a = 0.f;
#pragma unroll
    for (int i = 0; i < NR_; ++i)
        a += partial[(size_t)(w * NR_ + i) * D_ + d];
    red[w][lane] = a;
    __syncthreads();
    if (w == 0) {
        float s = ((red[0][lane] + red[1][lane]) + (red[2][lane] + red[3][lane]))
                  + red[4][lane];
        out[d] = (s > 0.f) ? 1.f : ((s < 0.f) ? -1.f : 0.f);
    }
}

extern "C" void kernel_launch(void* const* d_in, const int* in_sizes, int n_in,
                              void* d_out, int out_size, void* d_ws, size_t ws_size,
                              hipStream_t stream) {
    const float* x       = (const float*)d_in[0];
    const float* proj_w  = (const float*)d_in[1];
    const float* pos_hv  = (const float*)d_in[2];
    const float* pol_hv  = (const float*)d_in[3];
    const float* time_hv = (const float*)d_in[4];
    float* out = (float*)d_out;

    // ws layout: counts_q (15000 float4, 240 KB) at 0; partial (125*D f32,
    // 2 MB) at 256 KiB.  Total ~2.25 MB.
    float* counts_q = (float*)d_ws;
    float* partial  = (float*)((char*)d_ws + (256u << 10));

    {
        int total = T_ * P_ * NB_;
        k_counts<<<dim3((total + 255) / 256), dim3(256), 0, stream>>>(x, counts_q);
    }
    {
        dim3 grid(D_ / 256, GY_);
        k_encode<<<grid, dim3(256), 0, stream>>>((const float4*)counts_q, proj_w,
                                                 pos_hv, pol_hv, time_hv, partial);
    }
    k_reduce<<<dim3(D_ / 64), dim3(64, TR_), 0, stream>>>(partial, out);
}

// Round 8
// 45.704 us; speedup vs baseline: 1.7412x; 1.0468x over previous
//
#include <hip/hip_runtime.h>
#include <hip/hip_bf16.h>

// GraspHD encoder:
//   counts[t,p,n] = sum of 8x8 block of x            (T=100, P=2, NB=300)
//   bundled[d]    = sum_{t,p,n} sin(counts*w[d]) * pos[n,d]*pol[p,d]*time[t,d]
//   out[d]        = sign(bundled[d])                 (D=4096)
// pos/pol/time are exactly +-1.0f: fold the sign product into the sin
// argument's sign bit (sin(s*x) = s*sin(x)).
// sin = HW v_sin (input in REVOLUTIONS, range +-256; max |arg| ~41 rev),
// w pre-scaled by 1/2pi.
//
// R7: inner quad computed with packed f32 ops -- muls and accumulates as
// float2 ext-vectors so the backend emits v_pk_mul_f32 / v_pk_add_f32
// (full-rate dual f32): per-quad issue cost 56 -> 48 cycles.
// Time signs loaded per-k (R5 style; R6's hoist+VGPR-cap regressed).

#define T_ 100
#define P_ 2
#define H_ 120
#define W_ 160
#define BS_ 8
#define WB_ 20
#define NB_ 300
#define D_ 4096
#define NTC_ 50            // t-pairs
#define NR_ 25             // n-ranges, 12 n each
#define TR_ 5              // tc-ranges, 10 tc each
#define GY_ (NR_ * TR_)    // 125 encode y-blocks

typedef float f32x2 __attribute__((ext_vector_type(2)));

static __device__ __forceinline__ f32x2 u2f(unsigned a, unsigned b) {
    f32x2 r;
    r.x = __uint_as_float(a);
    r.y = __uint_as_float(b);
    return r;
}

// ---------------- kernel 1: per-block event counts (quad layout) ----------
// cq[((tc*300)+n)*4 + tl*2 + p]
__global__ __launch_bounds__(256) void k_counts(const float* __restrict__ x,
                                                float* __restrict__ cq) {
    int idx = blockIdx.x * 256 + threadIdx.x;           // (t*P + p)*NB + n
    if (idx >= T_ * P_ * NB_) return;
    int n  = idx % NB_;
    int tp = idx / NB_;
    int p  = tp & 1;
    int t  = tp >> 1;
    int hb = n / WB_;
    int wb = n % WB_;
    const float* base = x + ((size_t)tp * H_ + hb * BS_) * W_ + wb * BS_;
    float s = 0.f;
#pragma unroll
    for (int i = 0; i < BS_; ++i) {
        const float4* row = reinterpret_cast<const float4*>(base + i * W_);
        float4 a = row[0];
        float4 b = row[1];
        s += a.x + a.y + a.z + a.w + b.x + b.y + b.z + b.w;
    }
    cq[(((size_t)(t >> 1) * NB_ + n) << 2) + (t & 1) * 2 + p] = s;
}

// ---------------- kernel 2: main bind+bundle partial sums ----------------
// grid (D/256, GY_).  y -> (tcr, nr): tc in [tcr*10,+10), n in [nr*12,+12).
__global__ __launch_bounds__(256) void k_encode(const float4* __restrict__ cq,
                                                const float* __restrict__ proj_w,
                                                const float* __restrict__ pos_hv,
                                                const float* __restrict__ pol_hv,
                                                const float* __restrict__ time_hv,
                                                float* __restrict__ partial) {
    const int d   = blockIdx.x * 256 + threadIdx.x;
    const int tcr = blockIdx.y / NR_;
    const int nr  = blockIdx.y - tcr * NR_;
    const int n0  = nr * 12;
    const int tc0 = tcr * 10;

    const unsigned SGN = 0x80000000u;
    const float wp = proj_w[d] * 0.15915494309189535f;   // 1/(2*pi)
    const unsigned uw  = __float_as_uint(wp);
    const unsigned pl0 = __float_as_uint(pol_hv[d]) & SGN;
    const unsigned pl1 = __float_as_uint(pol_hv[D_ + d]) & SGN;

    // hoist 12 pos sign words, pre-xored with w and polarity (registers)
    unsigned X0[12], X1[12];
#pragma unroll
    for (int j = 0; j < 12; ++j) {
        unsigned mn = __float_as_uint(pos_hv[(size_t)(n0 + j) * D_ + d]) & SGN;
        X0[j] = (uw ^ pl0) ^ mn;
        X1[j] = (uw ^ pl1) ^ mn;
    }

    f32x2 accA = {0.f, 0.f};   // {t-even p0, t-even p1}
    f32x2 accB = {0.f, 0.f};   // {t-odd  p0, t-odd  p1}

    const float4* cb = cq + (size_t)tc0 * NB_ + n0;       // wave-uniform
    const float*  th = time_hv + (size_t)(tc0 * 2) * D_ + d;

#pragma unroll 2
    for (int k = 0; k < 10; ++k) {
        const unsigned ua = __float_as_uint(th[0]) & SGN;           // t = 2(tc0+k)
        const unsigned ub = __float_as_uint(th[(size_t)D_]) & SGN;  // t = 2(tc0+k)+1
        th += 2 * (size_t)D_;
        const float4* ck = cb + (size_t)k * NB_;
#pragma unroll
        for (int j = 0; j < 12; ++j) {
            float4 c = ck[j];                             // contiguous s_loads
            f32x2 c01; c01.x = c.x; c01.y = c.y;
            f32x2 c23; c23.x = c.z; c23.y = c.w;
            f32x2 wa = u2f(X0[j] ^ ua, X1[j] ^ ua);
            f32x2 wb = u2f(X0[j] ^ ub, X1[j] ^ ub);
            f32x2 pa = c01 * wa;                          // v_pk_mul_f32
            f32x2 pb = c23 * wb;
            f32x2 sa, sb;
            sa.x = __builtin_amdgcn_sinf(pa.x);
            sa.y = __builtin_amdgcn_sinf(pa.y);
            sb.x = __builtin_amdgcn_sinf(pb.x);
            sb.y = __builtin_amdgcn_sinf(pb.y);
            accA += sa;                                   // v_pk_add_f32
            accB += sb;
        }
    }

    partial[(size_t)blockIdx.y * D_ + d] =
        (accA.x + accA.y) + (accB.x + accB.y);
}

// ---------------- kernel 3: single-launch reduce + sign ------------------
// grid 64 blocks, block (64,5) = 5 waves. Wave w sums rows [w*25, w*25+25)
// for its 64 d's; LDS combine; wave 0 writes sign. Deterministic order.
__global__ __launch_bounds__(320) void k_reduce(const float* __restrict__ partial,
                                                float* __restrict__ out) {
    __shared__ float red[TR_][64];
    const int lane = threadIdx.x;          // 0..63
    const int w    = threadIdx.y;          // 0..4
    const int d    = blockIdx.x * 64 + lane;
    float a = 0.f;
#pragma unroll
    for (int i = 0; i < NR_; ++i)
        a += partial[(size_t)(w * NR_ + i) * D_ + d];
    red[w][lane] = a;
    __syncthreads();
    if (w == 0) {
        float s = ((red[0][lane] + red[1][lane]) + (red[2][lane] + red[3][lane]))
                  + red[4][lane];
        out[d] = (s > 0.f) ? 1.f : ((s < 0.f) ? -1.f : 0.f);
    }
}

extern "C" void kernel_launch(void* const* d_in, const int* in_sizes, int n_in,
                              void* d_out, int out_size, void* d_ws, size_t ws_size,
                              hipStream_t stream) {
    const float* x       = (const float*)d_in[0];
    const float* proj_w  = (const float*)d_in[1];
    const float* pos_hv  = (const float*)d_in[2];
    const float* pol_hv  = (const float*)d_in[3];
    const float* time_hv = (const float*)d_in[4];
    float* out = (float*)d_out;

    // ws layout: counts_q (15000 float4, 240 KB) at 0; partial (125*D f32,
    // 2 MB) at 256 KiB.  Total ~2.25 MB.
    float* counts_q = (float*)d_ws;
    float* partial  = (float*)((char*)d_ws + (256u << 10));

    {
        int total = T_ * P_ * NB_;
        k_counts<<<dim3((total + 255) / 256), dim3(256), 0, stream>>>(x, counts_q);
    }
    {
        dim3 grid(D_ / 256, GY_);
        k_encode<<<grid, dim3(256), 0, stream>>>((const float4*)counts_q, proj_w,
                                                 pos_hv, pol_hv, time_hv, partial);
    }
    k_reduce<<<dim3(D_ / 64), dim3(64, TR_), 0, stream>>>(partial, out);
}

// Round 9
// 39.651 us; speedup vs baseline: 2.0070x; 1.1527x over previous
//
#include <hip/hip_runtime.h>
#include <hip/hip_bf16.h>

// GraspHD encoder:
//   counts[t,p,n] = sum of 8x8 block of x            (T=100, P=2, NB=300)
//   bundled[d]    = sum_{t,p,n} sin(counts*w[d]) * pos[n,d]*pol[p,d]*time[t,d]
//   out[d]        = sign(bundled[d])                 (D=4096)
// HVs are EXACTLY +-1.0f. Time sign folds into the sin argument (xor on
// wp's sign bit, amortized per k); pos*pol applied as a +-1.0 float
// multiplier through v_pk_fma_f32. sin = HW v_sin (REVOLUTIONS, range
// +-256; max |arg| ~46 rev), w pre-scaled by 1/2pi.
//
// R8: each thread processes TWO d's (d, d+2048): count s_loads shared,
// 8 independent mul->sin->fma chains per wave (trans-pipe ILP), loop
// overhead halved. Grid (8, 250): 2000 blocks, 5 t-pairs x 12 n each.

#define T_ 100
#define P_ 2
#define H_ 120
#define W_ 160
#define BS_ 8
#define WB_ 20
#define NB_ 300
#define D_ 4096
#define NTC_ 50            // t-pairs total
#define NR_ 25             // n-ranges, 12 n each

typedef float f32x2 __attribute__((ext_vector_type(2)));

static __device__ __forceinline__ f32x2 splat(float v) {
    f32x2 r; r.x = v; r.y = v; return r;
}

// ---------------- kernel 1: per-block event counts (quad layout) ----------
// cq[((tc*300)+n)*4 + tl*2 + p]
__global__ __launch_bounds__(256) void k_counts(const float* __restrict__ x,
                                                float* __restrict__ cq) {
    int idx = blockIdx.x * 256 + threadIdx.x;           // (t*P + p)*NB + n
    if (idx >= T_ * P_ * NB_) return;
    int n  = idx % NB_;
    int tp = idx / NB_;
    int p  = tp & 1;
    int t  = tp >> 1;
    int hb = n / WB_;
    int wb = n % WB_;
    const float* base = x + ((size_t)tp * H_ + hb * BS_) * W_ + wb * BS_;
    float s = 0.f;
#pragma unroll
    for (int i = 0; i < BS_; ++i) {
        const float4* row = reinterpret_cast<const float4*>(base + i * W_);
        float4 a = row[0];
        float4 b = row[1];
        s += a.x + a.y + a.z + a.w + b.x + b.y + b.z + b.w;
    }
    cq[(((size_t)(t >> 1) * NB_ + n) << 2) + (t & 1) * 2 + p] = s;
}

// ---------------- kernel 2: main bind+bundle partial sums ----------------
// grid (8, 25*NTC_/TCB). y -> (tcg, nr): tc in [tcg*TCB,+TCB), n in [nr*12,+12).
// Each thread: d = bx*256+tid (in [0,2048)) and d2 = d + 2048.
template<int TCB>
__global__ __launch_bounds__(256) void k_encode(const float4* __restrict__ cq,
                                                const float* __restrict__ proj_w,
                                                const float* __restrict__ pos_hv,
                                                const float* __restrict__ pol_hv,
                                                const float* __restrict__ time_hv,
                                                float* __restrict__ partial) {
    const int d   = blockIdx.x * 256 + threadIdx.x;      // [0, 2048)
    const int y   = blockIdx.y;
    const int tcg = y / NR_;
    const int nr  = y - tcg * NR_;
    const int n0  = nr * 12;
    const int tc0 = tcg * TCB;
    const int t0  = tc0 * 2;

    const unsigned SGN = 0x80000000u;
    const unsigned uw  = __float_as_uint(proj_w[d]        * 0.15915494309189535f);
    const unsigned uw2 = __float_as_uint(proj_w[d + 2048] * 0.15915494309189535f);

    f32x2 POL;  POL.x  = pol_hv[d];          POL.y  = pol_hv[D_ + d];
    f32x2 POL2; POL2.x = pol_hv[d + 2048];   POL2.y = pol_hv[D_ + d + 2048];

    // hoist raw pos values (+-1.0f) for both d's
    float pf[12], pf2[12];
#pragma unroll
    for (int j = 0; j < 12; ++j) {
        pf[j]  = pos_hv[(size_t)(n0 + j) * D_ + d];
        pf2[j] = pos_hv[(size_t)(n0 + j) * D_ + d + 2048];
    }

    f32x2 accA = {0.f, 0.f}, accB = {0.f, 0.f};
    f32x2 accA2 = {0.f, 0.f}, accB2 = {0.f, 0.f};

    const float4* cb = cq + (size_t)tc0 * NB_ + n0;       // wave-uniform
    const float*  th = time_hv + (size_t)t0 * D_ + d;

#pragma unroll
    for (int k = 0; k < TCB; ++k) {
        // time values are +-1.0f: xor their sign bit into wp (sin(c*(+-wp)))
        const unsigned sa  = __float_as_uint(th[(size_t)(2 * k) * D_])            & SGN;
        const unsigned sb  = __float_as_uint(th[(size_t)(2 * k + 1) * D_])        & SGN;
        const unsigned sa2 = __float_as_uint(th[(size_t)(2 * k) * D_ + 2048])     & SGN;
        const unsigned sb2 = __float_as_uint(th[(size_t)(2 * k + 1) * D_ + 2048]) & SGN;
        const f32x2 wA  = splat(__uint_as_float(uw  ^ sa));
        const f32x2 wB  = splat(__uint_as_float(uw  ^ sb));
        const f32x2 wA2 = splat(__uint_as_float(uw2 ^ sa2));
        const f32x2 wB2 = splat(__uint_as_float(uw2 ^ sb2));
        const float4* ck = cb + (size_t)k * NB_;
#pragma unroll
        for (int j = 0; j < 12; ++j) {
            float4 c = ck[j];                             // shared s_load quad
            f32x2 c01; c01.x = c.x; c01.y = c.y;          // t-even {p0,p1}
            f32x2 c23; c23.x = c.z; c23.y = c.w;          // t-odd  {p0,p1}
            f32x2 G  = splat(pf[j])  * POL;               // pos*pol as +-1.0
            f32x2 G2 = splat(pf2[j]) * POL2;

            f32x2 pa  = c01 * wA;                         // v_pk_mul_f32
            f32x2 pb  = c23 * wB;
            f32x2 pa2 = c01 * wA2;
            f32x2 pb2 = c23 * wB2;
            f32x2 s1, s2, s3, s4;
            s1.x = __builtin_amdgcn_sinf(pa.x);
            s1.y = __builtin_amdgcn_sinf(pa.y);
            s2.x = __builtin_amdgcn_sinf(pb.x);
            s2.y = __builtin_amdgcn_sinf(pb.y);
            s3.x = __builtin_amdgcn_sinf(pa2.x);
            s3.y = __builtin_amdgcn_sinf(pa2.y);
            s4.x = __builtin_amdgcn_sinf(pb2.x);
            s4.y = __builtin_amdgcn_sinf(pb2.y);
            accA  += s1 * G;                              // v_pk_fma_f32
            accB  += s2 * G;
            accA2 += s3 * G2;
            accB2 += s4 * G2;
        }
    }

    partial[(size_t)y * D_ + d]        = (accA.x + accB.x) + (accA.y + accB.y);
    partial[(size_t)y * D_ + d + 2048] = (accA2.x + accB2.x) + (accA2.y + accB2.y);
}

// ---------------- kernel 3: single-launch reduce + sign ------------------
// grid 64 blocks, block (64,5) = 5 waves. Wave w sums GY/5 rows for its
// 64 d's; LDS combine; wave 0 writes sign. Deterministic order.
template<int GY>
__global__ __launch_bounds__(320) void k_reduce(const float* __restrict__ partial,
                                                float* __restrict__ out) {
    __shared__ float red[5][64];
    const int lane = threadIdx.x;          // 0..63
    const int w    = threadIdx.y;          // 0..4
    const int d    = blockIdx.x * 64 + lane;
    float a = 0.f;
#pragma unroll
    for (int i = 0; i < GY / 5; ++i)
        a += partial[(size_t)(w * (GY / 5) + i) * D_ + d];
    red[w][lane] = a;
    __syncthreads();
    if (w == 0) {
        float s = ((red[0][lane] + red[1][lane]) + (red[2][lane] + red[3][lane]))
                  + red[4][lane];
        out[d] = (s > 0.f) ? 1.f : ((s < 0.f) ? -1.f : 0.f);
    }
}

extern "C" void kernel_launch(void* const* d_in, const int* in_sizes, int n_in,
                              void* d_out, int out_size, void* d_ws, size_t ws_size,
                              hipStream_t stream) {
    const float* x       = (const float*)d_in[0];
    const float* proj_w  = (const float*)d_in[1];
    const float* pos_hv  = (const float*)d_in[2];
    const float* pol_hv  = (const float*)d_in[3];
    const float* time_hv = (const float*)d_in[4];
    float* out = (float*)d_out;

    // ws layout: counts_q (15000 float4, 240 KB) at 0; partial at 256 KiB.
    float* counts_q = (float*)d_ws;
    float* partial  = (float*)((char*)d_ws + (256u << 10));

    {
        int total = T_ * P_ * NB_;
        k_counts<<<dim3((total + 255) / 256), dim3(256), 0, stream>>>(x, counts_q);
    }

    const size_t need250 = (256u << 10) + (size_t)250 * D_ * 4 + 1024;
    if (ws_size >= need250) {
        // 2000 blocks: 5 t-pairs x 12 n per block, 250 partial rows
        k_encode<5><<<dim3(8, 250), dim3(256), 0, stream>>>(
            (const float4*)counts_q, proj_w, pos_hv, pol_hv, time_hv, partial);
        k_reduce<250><<<dim3(D_ / 64), dim3(64, 5), 0, stream>>>(partial, out);
    } else {
        // fallback: 1000 blocks, 125 partial rows (2 MB)
        k_encode<10><<<dim3(8, 125), dim3(256), 0, stream>>>(
            (const float4*)counts_q, proj_w, pos_hv, pol_hv, time_hv, partial);
        k_reduce<125><<<dim3(D_ / 64), dim3(64, 5), 0, stream>>>(partial, out);
    }
}

// Round 10
// 39.108 us; speedup vs baseline: 2.0349x; 1.0139x over previous
//
#include <hip/hip_runtime.h>
#include <hip/hip_bf16.h>

// GraspHD encoder:
//   counts[t,p,n] = sum of 8x8 block of x            (T=100, P=2, NB=300)
//   bundled[d]    = sum_{t,p,n} sin(counts*w[d]) * pos[n,d]*pol[p,d]*time[t,d]
//   out[d]        = sign(bundled[d])                 (D=4096)
// HVs are EXACTLY +-1.0f.  Sign decomposition:
//   time sign  -> xored into the sin ARGUMENT (sin(c*(+-w)) = +-sin(c*w))
//   pos sign   -> +-1.0f multiplier via v_pk_fma_f32 (pf[j])
//   pol sign   -> applied ONCE at the epilogue (constant per d)
// sin = HW v_sin (REVOLUTIONS, range +-256; max |arg| ~46 rev), w
// pre-scaled by 1/2pi.  Inner economy: 16 insts per 8 terms.
//
// R9: 1 d per thread (VGPR ~50 -> 8 waves/SIMD) with j-PAIR inner loop
// keeping 8 independent mul->sin->fma chains per wave.  Grid (16,125) =
// 2000 blocks, 125 partial rows (2.25 MB ws, no runtime branch).

#define T_ 100
#define P_ 2
#define H_ 120
#define W_ 160
#define BS_ 8
#define WB_ 20
#define NB_ 300
#define D_ 4096
#define NR_ 25             // n-ranges, 12 n each
#define TCB_ 10            // t-pairs per block
#define GY_ 125            // partial rows

typedef float f32x2 __attribute__((ext_vector_type(2)));

static __device__ __forceinline__ f32x2 splat(float v) {
    f32x2 r; r.x = v; r.y = v; return r;
}

// ---------------- kernel 1: per-block event counts (quad layout) ----------
// cq[((tc*300)+n)*4 + tl*2 + p]
__global__ __launch_bounds__(256) void k_counts(const float* __restrict__ x,
                                                float* __restrict__ cq) {
    int idx = blockIdx.x * 256 + threadIdx.x;           // (t*P + p)*NB + n
    if (idx >= T_ * P_ * NB_) return;
    int n  = idx % NB_;
    int tp = idx / NB_;
    int p  = tp & 1;
    int t  = tp >> 1;
    int hb = n / WB_;
    int wb = n % WB_;
    const float* base = x + ((size_t)tp * H_ + hb * BS_) * W_ + wb * BS_;
    float s = 0.f;
#pragma unroll
    for (int i = 0; i < BS_; ++i) {
        const float4* row = reinterpret_cast<const float4*>(base + i * W_);
        float4 a = row[0];
        float4 b = row[1];
        s += a.x + a.y + a.z + a.w + b.x + b.y + b.z + b.w;
    }
    cq[(((size_t)(t >> 1) * NB_ + n) << 2) + (t & 1) * 2 + p] = s;
}

// ---------------- kernel 2: main bind+bundle partial sums ----------------
// grid (16, 125).  y -> (tcg, nr): tc in [tcg*10,+10), n in [nr*12,+12).
// Each thread owns one d.  Inner loop: j-pairs (2 n at a time) -> 8
// independent sin chains; accumulate sin*pos into {p0,p1} lanes; pol at end.
__global__ __launch_bounds__(256) void k_encode(const float4* __restrict__ cq,
                                                const float* __restrict__ proj_w,
                                                const float* __restrict__ pos_hv,
                                                const float* __restrict__ pol_hv,
                                                const float* __restrict__ time_hv,
                                                float* __restrict__ partial) {
    const int d   = blockIdx.x * 256 + threadIdx.x;
    const int y   = blockIdx.y;
    const int tcg = y / NR_;
    const int nr  = y - tcg * NR_;
    const int n0  = nr * 12;
    const int tc0 = tcg * TCB_;
    const int t0  = tc0 * 2;

    const unsigned SGN = 0x80000000u;
    const unsigned uw  = __float_as_uint(proj_w[d] * 0.15915494309189535f);

    // hoist raw pos values (+-1.0f); pol deferred to epilogue
    float pf[12];
#pragma unroll
    for (int j = 0; j < 12; ++j)
        pf[j] = pos_hv[(size_t)(n0 + j) * D_ + d];

    f32x2 accA = {0.f, 0.f};   // t-even {p0, p1} partial (pol not applied)
    f32x2 accB = {0.f, 0.f};   // t-odd  {p0, p1}

    const float4* cb = cq + (size_t)tc0 * NB_ + n0;       // wave-uniform
    const float*  th = time_hv + (size_t)t0 * D_ + d;

#pragma unroll 2
    for (int k = 0; k < TCB_; ++k) {
        const unsigned sa = __float_as_uint(th[(size_t)(2 * k) * D_])     & SGN;
        const unsigned sb = __float_as_uint(th[(size_t)(2 * k + 1) * D_]) & SGN;
        const f32x2 wA = splat(__uint_as_float(uw ^ sa));   // t-even +-w
        const f32x2 wB = splat(__uint_as_float(uw ^ sb));   // t-odd  +-w
        const float4* ck = cb + (size_t)k * NB_;
#pragma unroll
        for (int j = 0; j < 12; j += 2) {
            float4 cj0 = ck[j];                           // contiguous s_loads
            float4 cj1 = ck[j + 1];
            f32x2 a01; a01.x = cj0.x; a01.y = cj0.y;      // n=j,   t-even {p0,p1}
            f32x2 a23; a23.x = cj0.z; a23.y = cj0.w;      // n=j,   t-odd
            f32x2 b01; b01.x = cj1.x; b01.y = cj1.y;      // n=j+1, t-even
            f32x2 b23; b23.x = cj1.z; b23.y = cj1.w;      // n=j+1, t-odd

            f32x2 pa0 = a01 * wA;                         // v_pk_mul_f32 x4
            f32x2 pa1 = a23 * wB;
            f32x2 pb0 = b01 * wA;
            f32x2 pb1 = b23 * wB;

            f32x2 s1, s2, s3, s4;                         // 8 independent sins
            s1.x = __builtin_amdgcn_sinf(pa0.x);
            s1.y = __builtin_amdgcn_sinf(pa0.y);
            s2.x = __builtin_amdgcn_sinf(pa1.x);
            s2.y = __builtin_amdgcn_sinf(pa1.y);
            s3.x = __builtin_amdgcn_sinf(pb0.x);
            s3.y = __builtin_amdgcn_sinf(pb0.y);
            s4.x = __builtin_amdgcn_sinf(pb1.x);
            s4.y = __builtin_amdgcn_sinf(pb1.y);

            const f32x2 g0 = splat(pf[j]);                // pos sign as +-1.0
            const f32x2 g1 = splat(pf[j + 1]);
            accA += s1 * g0;                              // v_pk_fma_f32 x4
            accB += s2 * g0;
            accA += s3 * g1;
            accB += s4 * g1;
        }
    }

    // epilogue: apply polarity (+-1.0f), combine t-even/t-odd
    const float pol0 = pol_hv[d];
    const float pol1 = pol_hv[D_ + d];
    partial[(size_t)y * D_ + d] =
        (accA.x + accB.x) * pol0 + (accA.y + accB.y) * pol1;
}

// ---------------- kernel 3: single-launch reduce + sign ------------------
// grid 64 blocks, block (64,5) = 5 waves. Wave w sums 25 rows for its
// 64 d's; LDS combine; wave 0 writes sign. Deterministic order.
__global__ __launch_bounds__(320) void k_reduce(const float* __restrict__ partial,
                                                float* __restrict__ out) {
    __shared__ float red[5][64];
    const int lane = threadIdx.x;          // 0..63
    const int w    = threadIdx.y;          // 0..4
    const int d    = blockIdx.x * 64 + lane;
    float a = 0.f;
#pragma unroll
    for (int i = 0; i < GY_ / 5; ++i)
        a += partial[(size_t)(w * (GY_ / 5) + i) * D_ + d];
    red[w][lane] = a;
    __syncthreads();
    if (w == 0) {
        float s = ((red[0][lane] + red[1][lane]) + (red[2][lane] + red[3][lane]))
                  + red[4][lane];
        out[d] = (s > 0.f) ? 1.f : ((s < 0.f) ? -1.f : 0.f);
    }
}

extern "C" void kernel_launch(void* const* d_in, const int* in_sizes, int n_in,
                              void* d_out, int out_size, void* d_ws, size_t ws_size,
                              hipStream_t stream) {
    const float* x       = (const float*)d_in[0];
    const float* proj_w  = (const float*)d_in[1];
    const float* pos_hv  = (const float*)d_in[2];
    const float* pol_hv  = (const float*)d_in[3];
    const float* time_hv = (const float*)d_in[4];
    float* out = (float*)d_out;

    // ws layout: counts_q (15000 float4, 240 KB) at 0; partial (125*D f32,
    // 2 MB) at 256 KiB.  Total 2.25 MB (proven fit since R4).
    float* counts_q = (float*)d_ws;
    float* partial  = (float*)((char*)d_ws + (256u << 10));

    {
        int total = T_ * P_ * NB_;
        k_counts<<<dim3((total + 255) / 256), dim3(256), 0, stream>>>(x, counts_q);
    }
    k_encode<<<dim3(16, GY_), dim3(256), 0, stream>>>(
        (const float4*)counts_q, proj_w, pos_hv, pol_hv, time_hv, partial);
    k_reduce<<<dim3(D_ / 64), dim3(64, 5), 0, stream>>>(partial, out);
}

// Round 11
// 37.961 us; speedup vs baseline: 2.0963x; 1.0302x over previous
//
#include <hip/hip_runtime.h>
#include <hip/hip_bf16.h>

// GraspHD encoder:
//   counts[t,p,n] = sum of 8x8 block of x            (T=100, P=2, NB=300)
//   bundled[d]    = sum_{t,p,n} sin(counts*w[d]) * pos[n,d]*pol[p,d]*time[t,d]
//   out[d]        = sign(bundled[d])                 (D=4096)
// HVs are EXACTLY +-1.0f.  Sign decomposition:
//   time sign  -> xored into the sin ARGUMENT (sin(c*(+-w)) = +-sin(c*w))
//   pos sign   -> +-1.0f multiplier via v_pk_fma_f32 (pf[j])
//   pol sign   -> applied ONCE at the epilogue (constant per d)
// sin = HW v_sin (REVOLUTIONS, range +-256; max |arg| ~46 rev), w
// pre-scaled by 1/2pi.
//
// R10: k_counts parallelized 8x (was 24 blocks reading 15.4 MB cold HBM
// ~10us): one thread per (cell,row), shfl_xor tree over the 8-lane group,
// 1875 blocks. Encode: depth-1 software pipeline on per-k time loads.

#define T_ 100
#define P_ 2
#define H_ 120
#define W_ 160
#define BS_ 8
#define WB_ 20
#define HB_ 15
#define NB_ 300
#define D_ 4096
#define NR_ 25             // n-ranges, 12 n each
#define TCB_ 10            // t-pairs per block
#define GY_ 125            // partial rows

typedef float f32x2 __attribute__((ext_vector_type(2)));

static __device__ __forceinline__ f32x2 splat(float v) {
    f32x2 r; r.x = v; r.y = v; return r;
}

// ---------------- kernel 1: per-block event counts (quad layout) ----------
// 480000 threads: cell = gid>>3 (60000 cells), row = gid&7.
// cell = ((t*2+p)*15 + hb)*20 + wb  (wb fastest -> near-coalesced reads).
// 8 row-partials of a cell sit in consecutive lanes -> shfl_xor 1,2,4.
__global__ __launch_bounds__(256) void k_counts(const float* __restrict__ x,
                                                float* __restrict__ cq) {
    int gid  = blockIdx.x * 256 + threadIdx.x;
    int cell = gid >> 3;
    int row  = gid & 7;

    int wb = cell % WB_;
    int r1 = cell / WB_;
    int hb = r1 % HB_;
    int tp = r1 / HB_;

    const float4* rp = reinterpret_cast<const float4*>(
        x + ((size_t)tp * H_ + hb * BS_ + row) * W_ + wb * BS_);
    float4 a = rp[0];
    float4 b = rp[1];
    float s = (a.x + a.y + a.z + a.w) + (b.x + b.y + b.z + b.w);

    // reduce the 8 rows (consecutive lanes) via xor butterfly
    s += __shfl_xor(s, 1, 64);
    s += __shfl_xor(s, 2, 64);
    s += __shfl_xor(s, 4, 64);

    if (row == 0) {
        int t  = tp >> 1;
        int p  = tp & 1;
        int n  = hb * WB_ + wb;
        int tc = t >> 1;
        int tl = t & 1;
        cq[(((size_t)tc * NB_ + n) << 2) + tl * 2 + p] = s;
    }
}

// ---------------- kernel 2: main bind+bundle partial sums ----------------
// grid (16, 125).  y -> (tcg, nr): tc in [tcg*10,+10), n in [nr*12,+12).
// Each thread owns one d.  Inner loop: j-pairs (2 n at a time) -> 8
// independent sin chains; accumulate sin*pos into {p0,p1} lanes; pol at end.
__global__ __launch_bounds__(256) void k_encode(const float4* __restrict__ cq,
                                                const float* __restrict__ proj_w,
                                                const float* __restrict__ pos_hv,
                                                const float* __restrict__ pol_hv,
                                                const float* __restrict__ time_hv,
                                                float* __restrict__ partial) {
    const int d   = blockIdx.x * 256 + threadIdx.x;
    const int y   = blockIdx.y;
    const int tcg = y / NR_;
    const int nr  = y - tcg * NR_;
    const int n0  = nr * 12;
    const int tc0 = tcg * TCB_;
    const int t0  = tc0 * 2;

    const unsigned SGN = 0x80000000u;
    const unsigned uw  = __float_as_uint(proj_w[d] * 0.15915494309189535f);

    // hoist raw pos values (+-1.0f); pol deferred to epilogue
    float pf[12];
#pragma unroll
    for (int j = 0; j < 12; ++j)
        pf[j] = pos_hv[(size_t)(n0 + j) * D_ + d];

    f32x2 accA = {0.f, 0.f};   // t-even {p0, p1} partial (pol not applied)
    f32x2 accB = {0.f, 0.f};   // t-odd  {p0, p1}

    const float4* cb = cq + (size_t)tc0 * NB_ + n0;       // wave-uniform
    const float*  th = time_hv + (size_t)t0 * D_ + d;

    // depth-1 software pipeline on the per-k time-sign loads
    unsigned sa = __float_as_uint(th[0])          & SGN;
    unsigned sb = __float_as_uint(th[(size_t)D_]) & SGN;

#pragma unroll 2
    for (int k = 0; k < TCB_; ++k) {
        unsigned nsa = 0u, nsb = 0u;
        if (k + 1 < TCB_) {
            nsa = __float_as_uint(th[(size_t)(2 * k + 2) * D_]) & SGN;
            nsb = __float_as_uint(th[(size_t)(2 * k + 3) * D_]) & SGN;
        }
        const f32x2 wA = splat(__uint_as_float(uw ^ sa));   // t-even +-w
        const f32x2 wB = splat(__uint_as_float(uw ^ sb));   // t-odd  +-w
        const float4* ck = cb + (size_t)k * NB_;
#pragma unroll
        for (int j = 0; j < 12; j += 2) {
            float4 cj0 = ck[j];                           // contiguous s_loads
            float4 cj1 = ck[j + 1];
            f32x2 a01; a01.x = cj0.x; a01.y = cj0.y;      // n=j,   t-even {p0,p1}
            f32x2 a23; a23.x = cj0.z; a23.y = cj0.w;      // n=j,   t-odd
            f32x2 b01; b01.x = cj1.x; b01.y = cj1.y;      // n=j+1, t-even
            f32x2 b23; b23.x = cj1.z; b23.y = cj1.w;      // n=j+1, t-odd

            f32x2 pa0 = a01 * wA;                         // v_pk_mul_f32 x4
            f32x2 pa1 = a23 * wB;
            f32x2 pb0 = b01 * wA;
            f32x2 pb1 = b23 * wB;

            f32x2 s1, s2, s3, s4;                         // 8 independent sins
            s1.x = __builtin_amdgcn_sinf(pa0.x);
            s1.y = __builtin_amdgcn_sinf(pa0.y);
            s2.x = __builtin_amdgcn_sinf(pa1.x);
            s2.y = __builtin_amdgcn_sinf(pa1.y);
            s3.x = __builtin_amdgcn_sinf(pb0.x);
            s3.y = __builtin_amdgcn_sinf(pb0.y);
            s4.x = __builtin_amdgcn_sinf(pb1.x);
            s4.y = __builtin_amdgcn_sinf(pb1.y);

            const f32x2 g0 = splat(pf[j]);                // pos sign as +-1.0
            const f32x2 g1 = splat(pf[j + 1]);
            accA += s1 * g0;                              // v_pk_fma_f32 x4
            accB += s2 * g0;
            accA += s3 * g1;
            accB += s4 * g1;
        }
        sa = nsa;
        sb = nsb;
    }

    // epilogue: apply polarity (+-1.0f), combine t-even/t-odd
    const float pol0 = pol_hv[d];
    const float pol1 = pol_hv[D_ + d];
    partial[(size_t)y * D_ + d] =
        (accA.x + accB.x) * pol0 + (accA.y + accB.y) * pol1;
}

// ---------------- kernel 3: single-launch reduce + sign ------------------
// grid 64 blocks, block (64,5) = 5 waves. Wave w sums 25 rows for its
// 64 d's; LDS combine; wave 0 writes sign. Deterministic order.
__global__ __launch_bounds__(320) void k_reduce(const float* __restrict__ partial,
                                                float* __restrict__ out) {
    __shared__ float red[5][64];
    const int lane = threadIdx.x;          // 0..63
    const int w    = threadIdx.y;          // 0..4
    const int d    = blockIdx.x * 64 + lane;
    float a = 0.f;
#pragma unroll
    for (int i = 0; i < GY_ / 5; ++i)
        a += partial[(size_t)(w * (GY_ / 5) + i) * D_ + d];
    red[w][lane] = a;
    __syncthreads();
    if (w == 0) {
        float s = ((red[0][lane] + red[1][lane]) + (red[2][lane] + red[3][lane]))
                  + red[4][lane];
        out[d] = (s > 0.f) ? 1.f : ((s < 0.f) ? -1.f : 0.f);
    }
}

extern "C" void kernel_launch(void* const* d_in, const int* in_sizes, int n_in,
                              void* d_out, int out_size, void* d_ws, size_t ws_size,
                              hipStream_t stream) {
    const float* x       = (const float*)d_in[0];
    const float* proj_w  = (const float*)d_in[1];
    const float* pos_hv  = (const float*)d_in[2];
    const float* pol_hv  = (const float*)d_in[3];
    const float* time_hv = (const float*)d_in[4];
    float* out = (float*)d_out;

    // ws layout: counts_q (15000 float4, 240 KB) at 0; partial (125*D f32,
    // 2 MB) at 256 KiB.  Total 2.25 MB (proven fit since R4).
    float* counts_q = (float*)d_ws;
    float* partial  = (float*)((char*)d_ws + (256u << 10));

    // 480000 threads = 1875 blocks: one thread per (quad-cell, row)
    k_counts<<<dim3(1875), dim3(256), 0, stream>>>(x, counts_q);

    k_encode<<<dim3(16, GY_), dim3(256), 0, stream>>>(
        (const float4*)counts_q, proj_w, pos_hv, pol_hv, time_hv, partial);
    k_reduce<<<dim3(D_ / 64), dim3(64, 5), 0, stream>>>(partial, out);
}